// Round 2
// baseline (149.451 us; speedup 1.0000x reference)
//
#include <hip/hip_runtime.h>

#define C_DIM 512
#define N_PIX 1024
#define B_DIM 8
#define NHEAD 8
#define HDIM 64
#define NGRP 8
#define CG 64
#define EPSF 1e-5f

typedef __bf16 bf16x8_t __attribute__((ext_vector_type(8)));
typedef __bf16 bf16x4_t __attribute__((ext_vector_type(4)));
typedef float  f32x4_t  __attribute__((ext_vector_type(4)));
typedef unsigned int u32x4_t __attribute__((ext_vector_type(4)));

__device__ __forceinline__ __bf16 f2b(float f) {
  unsigned int u = __builtin_bit_cast(unsigned int, f);
  u += 0x7fffu + ((u >> 16) & 1u);
  unsigned short s = (unsigned short)(u >> 16);
  return __builtin_bit_cast(__bf16, s);
}

// truncating pack: two fp32 -> packed bf16 pair (low=a, high=b); P>=0 so safe
__device__ __forceinline__ unsigned int pack_trunc(float a, float b) {
  return (__builtin_bit_cast(unsigned int, a) >> 16) |
         (__builtin_bit_cast(unsigned int, b) & 0xffff0000u);
}

__device__ __forceinline__ void async16(const void* g, void* l) {
  __builtin_amdgcn_global_load_lds((const __attribute__((address_space(1))) void*)g,
                                   (__attribute__((address_space(3))) void*)l, 16, 0, 0);
}

// ---------------- prep: weight fp32->bf16 (blocks 0..1023) + GN stats (1024..1535) ----------------
__global__ __launch_bounds__(256) void prep_kernel(
    const float* __restrict__ qw, const float* __restrict__ kw,
    const float* __restrict__ vw, const float* __restrict__ pw,
    __bf16* __restrict__ wb,
    const float* __restrict__ x, float2* __restrict__ psum)
{
  if (blockIdx.x < 1024) {
    int idx = blockIdx.x * 256 + threadIdx.x;
    int mat = idx >> 16;
    int off = (idx & 65535) * 4;
    const float* src = (mat == 0) ? qw : (mat == 1) ? kw : (mat == 2) ? vw : pw;
    float4 v = *(const float4*)(src + off);
    bf16x4_t pk;
    pk[0] = f2b(v.x); pk[1] = f2b(v.y); pk[2] = f2b(v.z); pk[3] = f2b(v.w);
    *(bf16x4_t*)(wb + mat * (512 * 512) + off) = pk;
  } else {
    const int t = blockIdx.x - 1024;
    const int s = t & 7, bg = t >> 3;
    const float* xp = x + ((size_t)bg * CG + s * 8) * N_PIX;
    float sum = 0.f, sum2 = 0.f;
#pragma unroll
    for (int it = 0; it < 8; it++) {
      float4 v = ((const float4*)xp)[it * 256 + threadIdx.x];
      sum  += v.x + v.y + v.z + v.w;
      sum2 += v.x * v.x + v.y * v.y + v.z * v.z + v.w * v.w;
    }
#pragma unroll
    for (int off = 32; off; off >>= 1) {
      sum  += __shfl_xor(sum, off, 64);
      sum2 += __shfl_xor(sum2, off, 64);
    }
    __shared__ float red[8];
    const int lane = threadIdx.x & 63, wv = threadIdx.x >> 6;
    if (lane == 0) { red[wv] = sum; red[4 + wv] = sum2; }
    __syncthreads();
    if (threadIdx.x == 0) {
      float s1 = red[0] + red[1] + red[2] + red[3];
      float s2 = red[4] + red[5] + red[6] + red[7];
      psum[bg * 8 + s] = make_float2(s1, s2);
    }
  }
}

// ---------------- GroupNorm apply + transpose -> xnT bf16 [B][N][C] ----------------
// z-split over channel halves: 512 blocks (2/CU) instead of 256 (1/CU).
__global__ __launch_bounds__(256) void gn_apply_kernel(
    const float* __restrict__ x, const float2* __restrict__ psum,
    const float* __restrict__ gw, const float* __restrict__ gb,
    __bf16* __restrict__ xnT)
{
  const int n0 = blockIdx.x * 32, b = blockIdx.y, z = blockIdx.z;
  const int tid = threadIdx.x;
  __shared__ float mu_s[8], rs_s[8];
  __shared__ __align__(16) __bf16 tile[32 * 264];

  if (tid < 8) {
    float s1 = 0.f, s2 = 0.f;
#pragma unroll
    for (int i = 0; i < 8; i++) {
      float2 p = psum[(b * 8 + tid) * 8 + i];
      s1 += p.x; s2 += p.y;
    }
    const float inv = 1.f / (float)(CG * N_PIX);
    float mu = s1 * inv;
    float var = s2 * inv - mu * mu;
    mu_s[tid] = mu;
    rs_s[tid] = rsqrtf(var + EPSF);
  }
  __syncthreads();

  const float* xb = x + (size_t)b * C_DIM * N_PIX + n0;
  const int cl = tid >> 3;
  const int nq = (tid & 7) * 4;
#pragma unroll
  for (int co = 0; co < 8; co++) {
    const int cc = co * 32 + cl;
    const int c = z * 256 + cc;
    float4 v = *(const float4*)(xb + (size_t)c * N_PIX + nq);
    const int g = c >> 6;
    const float rs = rs_s[g];
    const float a = rs * gw[c];
    const float bb = gb[c] - mu_s[g] * a;
    tile[(nq + 0) * 264 + cc] = f2b(v.x * a + bb);
    tile[(nq + 1) * 264 + cc] = f2b(v.y * a + bb);
    tile[(nq + 2) * 264 + cc] = f2b(v.z * a + bb);
    tile[(nq + 3) * 264 + cc] = f2b(v.w * a + bb);
  }
  __syncthreads();

  __bf16* dst = xnT + ((size_t)b * N_PIX + n0) * C_DIM + z * 256;
  const int l32 = tid & 31, nr = tid >> 5;
#pragma unroll
  for (int no = 0; no < 4; no++) {
    const int n = no * 8 + nr;
    const int cc = l32 * 8;
    *(bf16x8_t*)(dst + (size_t)n * C_DIM + cc) =
        *(const bf16x8_t*)(tile + n * 264 + cc);
  }
}

// ---------------- 64x128 gemm_bt core (proj): counted-vmcnt pipelined panels ----------------
// Panel pi in [0,16) = 32 K-cols; ping-pong buffer pi&1; loads for pi+1 stay in flight
// across the consume barrier (T4). Raw barriers (no vmcnt drain).
__device__ __forceinline__ void gemm_core_64(
    const __bf16* __restrict__ A, const __bf16* __restrict__ B,
    __bf16* As, __bf16* Bs, f32x4_t acc[2][4])
{
  const int tid  = threadIdx.x;
  const int lane = tid & 63;
  const int wv   = tid >> 6;
  const int quad = lane >> 4;
  const int l16  = lane & 15;
  const int wm = (wv >> 1) * 32;
  const int wn = (wv & 1) * 64;

  f32x4_t zero = {0.f, 0.f, 0.f, 0.f};
#pragma unroll
  for (int i = 0; i < 2; i++)
#pragma unroll
    for (int j = 0; j < 4; j++) acc[i][j] = zero;

  const int chA  = wv * 64 + lane;
  const int rA = chA >> 2,  kA = (chA & 3) * 8;
  const int chB0 = wv * 64 + lane, chB1 = 256 + wv * 64 + lane;
  const int rB0 = chB0 >> 2, kB0 = (chB0 & 3) * 8;
  const int rB1 = chB1 >> 2, kB1 = (chB1 & 3) * 8;

  // prologue: stage panel 0 into buf 0 (left in flight; waited in phase 0)
  async16(A + (size_t)rA * 512 + kA,  As + (wv * 64) * 8);
  async16(B + (size_t)rB0 * 512 + kB0, Bs + (wv * 64) * 8);
  async16(B + (size_t)rB1 * 512 + kB1, Bs + (256 + wv * 64) * 8);

  for (int kt2 = 0; kt2 < 8; kt2++) {
#pragma unroll
    for (int pp = 0; pp < 2; pp++) {
      const int pi = kt2 * 2 + pp;
      if (pi < 15) {
        const int kc = (pi + 1) * 32;
        const int nb = (pi + 1) & 1;
        async16(A + (size_t)rA * 512 + kc + kA,  As + nb * 2048 + (wv * 64) * 8);
        async16(B + (size_t)rB0 * 512 + kc + kB0, Bs + nb * 4096 + (wv * 64) * 8);
        async16(B + (size_t)rB1 * 512 + kc + kB1, Bs + nb * 4096 + (256 + wv * 64) * 8);
        // wait only for panel pi's 3 loads; pi+1's 3 remain in flight
        asm volatile("s_waitcnt vmcnt(3)" ::: "memory");
      } else {
        asm volatile("s_waitcnt vmcnt(0)" ::: "memory");
      }
      __builtin_amdgcn_s_barrier();
      __builtin_amdgcn_sched_barrier(0);
      bf16x8_t af[2], bfr[4];
#pragma unroll
      for (int i = 0; i < 2; i++)
        af[i] = *(const bf16x8_t*)(As + pp * 2048 + (wm + i * 16 + l16) * 32 + quad * 8);
#pragma unroll
      for (int j = 0; j < 4; j++)
        bfr[j] = *(const bf16x8_t*)(Bs + pp * 4096 + (wn + j * 16 + l16) * 32 + quad * 8);
      __builtin_amdgcn_s_setprio(1);
#pragma unroll
      for (int i = 0; i < 2; i++)
#pragma unroll
        for (int j = 0; j < 4; j++)
          acc[i][j] = __builtin_amdgcn_mfma_f32_16x16x32_bf16(af[i], bfr[j], acc[i][j], 0, 0, 0);
      __builtin_amdgcn_s_setprio(0);
      __builtin_amdgcn_sched_barrier(0);
      __builtin_amdgcn_s_barrier();   // buf[pi&1] free for reuse after this
    }
  }
}

// ---------------- FUSED QKV gemm: one block computes Q,K,V 64x128 tiles ----------------
// grid (8=b, 8=n, 8=m). B (xnT tile) staged ONCE per panel, 24 MFMA/phase.
// Counted-vmcnt pipeline: panel pi+1's 5 loads in flight across the consume barrier.
__global__ __launch_bounds__(256, 2) void gemm_qkv_kernel(
    const __bf16* __restrict__ wqkv, const float* __restrict__ qb,
    const float* __restrict__ kb, const float* __restrict__ vb,
    const __bf16* __restrict__ xnT,
    __bf16* __restrict__ qT, __bf16* __restrict__ kT, __bf16* __restrict__ vbuf)
{
  // 40 KB: Aq(0) Ak(4096) Av(8192) each 2 panels x 2048; Bs(12288) 2 panels x 4096.
  __shared__ __align__(16) __bf16 smem[20480];
  __bf16* Bs = smem + 12288;
  const int b = blockIdx.x;
  const int n0 = blockIdx.y * 128;
  const int m0 = blockIdx.z * 64;
  const __bf16* Aq = wqkv + (size_t)m0 * 512;
  const __bf16* Ak = Aq + 512 * 512;
  const __bf16* Av = Ak + 512 * 512;
  const __bf16* Bx = xnT + ((size_t)b * N_PIX + n0) * 512;

  const int tid = threadIdx.x, lane = tid & 63, wv = tid >> 6;
  const int quad = lane >> 4, l16 = lane & 15;
  const int wm = (wv >> 1) * 32, wn = (wv & 1) * 64;

  const f32x4_t zero = {0.f, 0.f, 0.f, 0.f};
  f32x4_t acc[3][2][4];
#pragma unroll
  for (int m = 0; m < 3; m++)
#pragma unroll
    for (int i = 0; i < 2; i++)
#pragma unroll
      for (int j = 0; j < 4; j++) acc[m][i][j] = zero;

  const int chA = wv * 64 + lane;
  const int rA = chA >> 2, kA = (chA & 3) * 8;
  const int chB0 = wv * 64 + lane, chB1 = 256 + wv * 64 + lane;
  const int rB0 = chB0 >> 2, kB0 = (chB0 & 3) * 8;
  const int rB1 = chB1 >> 2, kB1 = (chB1 & 3) * 8;

  // prologue: stage panel 0 into buf 0
  async16(Aq + (size_t)rA * 512 + kA, smem + (wv * 64) * 8);
  async16(Ak + (size_t)rA * 512 + kA, smem + 4096 + (wv * 64) * 8);
  async16(Av + (size_t)rA * 512 + kA, smem + 8192 + (wv * 64) * 8);
  async16(Bx + (size_t)rB0 * 512 + kB0, Bs + (wv * 64) * 8);
  async16(Bx + (size_t)rB1 * 512 + kB1, Bs + (256 + wv * 64) * 8);

  for (int kt2 = 0; kt2 < 8; kt2++) {
#pragma unroll
    for (int pp = 0; pp < 2; pp++) {
      const int pi = kt2 * 2 + pp;
      if (pi < 15) {
        const int kc = (pi + 1) * 32;
        const int nb = (pi + 1) & 1;
        async16(Aq + (size_t)rA * 512 + kc + kA, smem + nb * 2048 + (wv * 64) * 8);
        async16(Ak + (size_t)rA * 512 + kc + kA, smem + 4096 + nb * 2048 + (wv * 64) * 8);
        async16(Av + (size_t)rA * 512 + kc + kA, smem + 8192 + nb * 2048 + (wv * 64) * 8);
        async16(Bx + (size_t)rB0 * 512 + kc + kB0, Bs + nb * 4096 + (wv * 64) * 8);
        async16(Bx + (size_t)rB1 * 512 + kc + kB1, Bs + nb * 4096 + (256 + wv * 64) * 8);
        // wait only for panel pi's 5 loads; pi+1's 5 remain in flight
        asm volatile("s_waitcnt vmcnt(5)" ::: "memory");
      } else {
        asm volatile("s_waitcnt vmcnt(0)" ::: "memory");
      }
      __builtin_amdgcn_s_barrier();
      __builtin_amdgcn_sched_barrier(0);
      bf16x8_t bfr[4];
#pragma unroll
      for (int j = 0; j < 4; j++)
        bfr[j] = *(const bf16x8_t*)(Bs + pp * 4096 + (wn + j * 16 + l16) * 32 + quad * 8);
#pragma unroll
      for (int m = 0; m < 3; m++) {
        bf16x8_t af[2];
#pragma unroll
        for (int i = 0; i < 2; i++)
          af[i] = *(const bf16x8_t*)(smem + m * 4096 + pp * 2048 + (wm + i * 16 + l16) * 32 + quad * 8);
        __builtin_amdgcn_s_setprio(1);
#pragma unroll
        for (int i = 0; i < 2; i++)
#pragma unroll
          for (int j = 0; j < 4; j++)
            acc[m][i][j] = __builtin_amdgcn_mfma_f32_16x16x32_bf16(af[i], bfr[j], acc[m][i][j], 0, 0, 0);
        __builtin_amdgcn_s_setprio(0);
      }
      __builtin_amdgcn_sched_barrier(0);
      __builtin_amdgcn_s_barrier();   // buffers free for next phase's loads
    }
  }

  // ---- epilogues (sequential, reuse smem; all coalesced via LDS transpose) ----
  const float qscale = 0.125f * 1.44269504f;   // HD^-0.5 * log2(e), folded into Q
#pragma unroll
  for (int mat = 0; mat < 2; mat++) {
    const float* bias = (mat == 0) ? qb : kb;
    const float sc = (mat == 0) ? qscale : 1.0f;
    __bf16* dst = (mat == 0) ? qT : kT;
#pragma unroll
    for (int i = 0; i < 2; i++) {
      const int crow = wm + i * 16 + quad * 4;
      const int o = m0 + crow;
      float b0 = bias[o], b1 = bias[o + 1], b2 = bias[o + 2], b3 = bias[o + 3];
#pragma unroll
      for (int j = 0; j < 4; j++) {
        const int nl = wn + j * 16 + l16;
        bf16x4_t pk;
        pk[0] = f2b((acc[mat][i][j][0] + b0) * sc);
        pk[1] = f2b((acc[mat][i][j][1] + b1) * sc);
        pk[2] = f2b((acc[mat][i][j][2] + b2) * sc);
        pk[3] = f2b((acc[mat][i][j][3] + b3) * sc);
        *(bf16x4_t*)(smem + nl * 72 + crow) = pk;
      }
    }
    __syncthreads();
#pragma unroll
    for (int it = 0; it < 4; it++) {
      const int n = it * 32 + (tid >> 3);
      const int c = (tid & 7) * 8;
      *(bf16x8_t*)(dst + ((size_t)b * N_PIX + n0 + n) * 512 + m0 + c) =
          *(const bf16x8_t*)(smem + n * 72 + c);
    }
    __syncthreads();
  }
  // V: [c][n] layout via stride-132 transpose
#pragma unroll
  for (int i = 0; i < 2; i++) {
    const int crow = wm + i * 16 + quad * 4;
    const int o = m0 + crow;
    float b0 = vb[o], b1 = vb[o + 1], b2 = vb[o + 2], b3 = vb[o + 3];
#pragma unroll
    for (int j = 0; j < 4; j++) {
      const int nl = wn + j * 16 + l16;
      smem[(crow + 0) * 132 + nl] = f2b(acc[2][i][j][0] + b0);
      smem[(crow + 1) * 132 + nl] = f2b(acc[2][i][j][1] + b1);
      smem[(crow + 2) * 132 + nl] = f2b(acc[2][i][j][2] + b2);
      smem[(crow + 3) * 132 + nl] = f2b(acc[2][i][j][3] + b3);
    }
  }
  __syncthreads();
  {
    const int c = tid >> 2;
    const int nch = (tid & 3) * 32;
    __bf16* vd = vbuf + ((size_t)b * 512 + m0 + c) * N_PIX + n0 + nch;
#pragma unroll
    for (int k = 0; k < 4; k++)
      *(bf16x8_t*)(vd + k * 8) = *(const bf16x8_t*)(smem + c * 132 + nch + k * 8);
  }
}

// ---------------- attention: 32 q/wave, permuted V, double-buffered, LDS-transposed out ----------------
// Raw barriers with lgkm-only drain: the 2-ahead K/V global prefetch stays in flight.
__global__ __launch_bounds__(256, 2) void attn_kernel(
    const __bf16* __restrict__ qT, const __bf16* __restrict__ kT,
    const __bf16* __restrict__ vbuf, __bf16* __restrict__ aT)
{
  __shared__ __align__(16) __bf16 Ks[2][64 * 72];
  __shared__ __align__(16) __bf16 Vp[2][64 * 72];
  const int bh = blockIdx.x;
  const int b = bh >> 3, head = bh & 7;
  const int n0 = blockIdx.y * 128;
  const int tid = threadIdx.x, lane = tid & 63, wv = tid >> 6;
  const int quad = lane >> 4, l16 = lane & 15;

  bf16x8_t qf[2][2];
#pragma unroll
  for (int qt = 0; qt < 2; qt++) {
    const __bf16* qp = qT + ((size_t)b * N_PIX + n0 + wv * 32 + qt * 16 + l16) * 512 + head * 64;
    qf[qt][0] = *(const bf16x8_t*)(qp + quad * 8);
    qf[qt][1] = *(const bf16x8_t*)(qp + 32 + quad * 8);
  }

  const __bf16* kp = kT + ((size_t)b * N_PIX) * 512 + head * 64;
  const __bf16* vp = vbuf + ((size_t)b * 512 + head * 64) * N_PIX;

  const int srow = tid >> 2, scol = (tid & 3) * 16;
  const int pr0 = scol >> 5, hh0 = (scol >> 4) & 1;
  const int pos0 = pr0 * 32 + ((scol >> 2) & 3) * 8 + hh0 * 4;
  const int mc1 = scol + 8;
  const int pr1 = mc1 >> 5, hh1 = (mc1 >> 4) & 1;
  const int pos1 = pr1 * 32 + ((mc1 >> 2) & 3) * 8 + hh1 * 4;

  bf16x8_t kreg0 = *(const bf16x8_t*)(kp + (size_t)srow * 512 + scol);
  bf16x8_t kreg1 = *(const bf16x8_t*)(kp + (size_t)srow * 512 + scol + 8);
  bf16x8_t vreg0 = *(const bf16x8_t*)(vp + (size_t)srow * N_PIX + scol);
  bf16x8_t vreg1 = *(const bf16x8_t*)(vp + (size_t)srow * N_PIX + scol + 8);
  {
    *(bf16x8_t*)(Ks[0] + srow * 72 + scol)     = kreg0;
    *(bf16x8_t*)(Ks[0] + srow * 72 + scol + 8) = kreg1;
    bf16x4_t lo, hi;
#pragma unroll
    for (int r = 0; r < 4; r++) { lo[r] = vreg0[r]; hi[r] = vreg0[4 + r]; }
    *(bf16x4_t*)(Vp[0] + srow * 72 + pos0)     = lo;
    *(bf16x4_t*)(Vp[0] + srow * 72 + pos0 + 8) = hi;
#pragma unroll
    for (int r = 0; r < 4; r++) { lo[r] = vreg1[r]; hi[r] = vreg1[4 + r]; }
    *(bf16x4_t*)(Vp[0] + srow * 72 + pos1)     = lo;
    *(bf16x4_t*)(Vp[0] + srow * 72 + pos1 + 8) = hi;
  }
  kreg0 = *(const bf16x8_t*)(kp + (size_t)(64 + srow) * 512 + scol);
  kreg1 = *(const bf16x8_t*)(kp + (size_t)(64 + srow) * 512 + scol + 8);
  vreg0 = *(const bf16x8_t*)(vp + (size_t)srow * N_PIX + 64 + scol);
  vreg1 = *(const bf16x8_t*)(vp + (size_t)srow * N_PIX + 64 + scol + 8);
  // LDS-write visibility only; tile-1 global prefetch stays in flight
  asm volatile("s_waitcnt lgkmcnt(0)" ::: "memory");
  __builtin_amdgcn_s_barrier();
  __builtin_amdgcn_sched_barrier(0);

  const f32x4_t zero = {0.f, 0.f, 0.f, 0.f};
  f32x4_t oacc[2][4];
#pragma unroll
  for (int qt = 0; qt < 2; qt++)
#pragma unroll
    for (int jc = 0; jc < 4; jc++) oacc[qt][jc] = zero;
  f32x4_t lsum4[2] = {zero, zero};

  for (int mt = 0; mt < 16; mt++) {
    const int cur = mt & 1, nxt = cur ^ 1;
    const __bf16* Kc = Ks[cur];
    const __bf16* Vc = Vp[cur];

    f32x4_t sacc[2][4];
    __builtin_amdgcn_s_setprio(1);
#pragma unroll
    for (int mb = 0; mb < 4; mb++) {
      bf16x8_t kf0 = *(const bf16x8_t*)(Kc + (mb * 16 + l16) * 72 + quad * 8);
      bf16x8_t kf1 = *(const bf16x8_t*)(Kc + (mb * 16 + l16) * 72 + 32 + quad * 8);
#pragma unroll
      for (int qt = 0; qt < 2; qt++) {
        f32x4_t s = zero;
        s = __builtin_amdgcn_mfma_f32_16x16x32_bf16(kf0, qf[qt][0], s, 0, 0, 0);
        s = __builtin_amdgcn_mfma_f32_16x16x32_bf16(kf1, qf[qt][1], s, 0, 0, 0);
        sacc[qt][mb] = s;
      }
    }
    __builtin_amdgcn_s_setprio(0);

    bf16x8_t pf[2][2];
#pragma unroll
    for (int qt = 0; qt < 2; qt++) {
      float p[4][4];
#pragma unroll
      for (int mb = 0; mb < 4; mb++)
#pragma unroll
        for (int r = 0; r < 4; r++) {
          p[mb][r] = __builtin_amdgcn_exp2f(sacc[qt][mb][r]);
          lsum4[qt][r] += p[mb][r];
        }
#pragma unroll
      for (int pr = 0; pr < 2; pr++) {
        u32x4_t u;
        u[0] = pack_trunc(p[2 * pr][0],     p[2 * pr][1]);
        u[1] = pack_trunc(p[2 * pr][2],     p[2 * pr][3]);
        u[2] = pack_trunc(p[2 * pr + 1][0], p[2 * pr + 1][1]);
        u[3] = pack_trunc(p[2 * pr + 1][2], p[2 * pr + 1][3]);
        pf[qt][pr] = __builtin_bit_cast(bf16x8_t, u);
      }
    }

    __builtin_amdgcn_s_setprio(1);
#pragma unroll
    for (int jc = 0; jc < 4; jc++) {
      const int vrow = (jc * 16 + l16) * 72;
#pragma unroll
      for (int pr = 0; pr < 2; pr++) {
        bf16x8_t vf = *(const bf16x8_t*)(Vc + vrow + pr * 32 + quad * 8);
#pragma unroll
        for (int qt = 0; qt < 2; qt++)
          oacc[qt][jc] = __builtin_amdgcn_mfma_f32_16x16x32_bf16(vf, pf[qt][pr], oacc[qt][jc], 0, 0, 0);
      }
    }
    __builtin_amdgcn_s_setprio(0);

    if (mt < 15) {
      *(bf16x8_t*)(Ks[nxt] + srow * 72 + scol)     = kreg0;
      *(bf16x8_t*)(Ks[nxt] + srow * 72 + scol + 8) = kreg1;
      bf16x4_t lo, hi;
#pragma unroll
      for (int r = 0; r < 4; r++) { lo[r] = vreg0[r]; hi[r] = vreg0[4 + r]; }
      *(bf16x4_t*)(Vp[nxt] + srow * 72 + pos0)     = lo;
      *(bf16x4_t*)(Vp[nxt] + srow * 72 + pos0 + 8) = hi;
#pragma unroll
      for (int r = 0; r < 4; r++) { lo[r] = vreg1[r]; hi[r] = vreg1[4 + r]; }
      *(bf16x4_t*)(Vp[nxt] + srow * 72 + pos1)     = lo;
      *(bf16x4_t*)(Vp[nxt] + srow * 72 + pos1 + 8) = hi;
      if (mt < 14) {
        kreg0 = *(const bf16x8_t*)(kp + (size_t)((mt + 2) * 64 + srow) * 512 + scol);
        kreg1 = *(const bf16x8_t*)(kp + (size_t)((mt + 2) * 64 + srow) * 512 + scol + 8);
        vreg0 = *(const bf16x8_t*)(vp + (size_t)srow * N_PIX + (mt + 2) * 64 + scol);
        vreg1 = *(const bf16x8_t*)(vp + (size_t)srow * N_PIX + (mt + 2) * 64 + scol + 8);
      }
      // LDS-write visibility only; next-tile global prefetch stays in flight
      asm volatile("s_waitcnt lgkmcnt(0)" ::: "memory");
      __builtin_amdgcn_s_barrier();
      __builtin_amdgcn_sched_barrier(0);
    }
  }

  // O epilogue: normalize, transpose through LDS (reuse Ks), coalesced stores
  __syncthreads();
  __bf16* Tr = &Ks[0][0];
#pragma unroll
  for (int qt = 0; qt < 2; qt++) {
    float lsum = lsum4[qt][0] + lsum4[qt][1] + lsum4[qt][2] + lsum4[qt][3];
    lsum += __shfl_xor(lsum, 16, 64);
    lsum += __shfl_xor(lsum, 32, 64);
    const float inv = 1.f / lsum;
    const int nl = wv * 32 + qt * 16 + l16;
#pragma unroll
    for (int jc = 0; jc < 4; jc++) {
      bf16x4_t o4;
#pragma unroll
      for (int r = 0; r < 4; r++) o4[r] = f2b(oacc[qt][jc][r] * inv);
      *(bf16x4_t*)(Tr + nl * 72 + jc * 16 + quad * 4) = o4;
    }
  }
  __syncthreads();
#pragma unroll
  for (int it = 0; it < 4; it++) {
    const int n = it * 32 + (tid >> 3);
    const int c = (tid & 7) * 8;
    *(bf16x8_t*)(aT + ((size_t)b * N_PIX + n0 + n) * 512 + head * 64 + c) =
        *(const bf16x8_t*)(Tr + n * 72 + c);
  }
}

// ---------------- proj gemm + bias + residual: 64x128 tiles, grid (8=b, 8=n, 8=m) ----------------
__global__ __launch_bounds__(256, 4) void gemm_proj_kernel(
    const __bf16* __restrict__ wp, const float* __restrict__ pb,
    const __bf16* __restrict__ aT, const float* __restrict__ x,
    float* __restrict__ out)
{
  __shared__ __align__(16) __bf16 smem[12288];
  __bf16* As = smem;
  __bf16* Bs = smem + 4096;
  const int b = blockIdx.x;
  const int n0 = blockIdx.y * 128;
  const int m0 = blockIdx.z * 64;
  const __bf16* A = wp + (size_t)m0 * 512;
  const __bf16* B = aT + ((size_t)b * N_PIX + n0) * 512;
  f32x4_t acc[2][4];
  gemm_core_64(A, B, As, Bs, acc);
  const int tid = threadIdx.x, lane = tid & 63, wv = tid >> 6;
  const int quad = lane >> 4, l16 = lane & 15;
  const int wm = (wv >> 1) * 32, wn = (wv & 1) * 64;
#pragma unroll
  for (int i = 0; i < 2; i++) {
    const int o = m0 + wm + i * 16 + quad * 4;
#pragma unroll
    for (int j = 0; j < 4; j++) {
      const int n = n0 + wn + j * 16 + l16;
#pragma unroll
      for (int r = 0; r < 4; r++) {
        size_t idx = ((size_t)b * 512 + o + r) * N_PIX + n;
        out[idx] = acc[i][j][r] + pb[o + r] + x[idx];
      }
    }
  }
}

extern "C" void kernel_launch(void* const* d_in, const int* in_sizes, int n_in,
                              void* d_out, int out_size, void* d_ws, size_t ws_size,
                              hipStream_t stream)
{
  (void)in_sizes; (void)n_in; (void)out_size; (void)ws_size;
  const float* x   = (const float*)d_in[0];
  const float* gnw = (const float*)d_in[1];
  const float* gnb = (const float*)d_in[2];
  const float* qw  = (const float*)d_in[3];
  const float* qb  = (const float*)d_in[4];
  const float* kw  = (const float*)d_in[5];
  const float* kb  = (const float*)d_in[6];
  const float* vw  = (const float*)d_in[7];
  const float* vb  = (const float*)d_in[8];
  const float* pw  = (const float*)d_in[9];
  const float* pb  = (const float*)d_in[10];
  float* out = (float*)d_out;

  char* ws = (char*)d_ws;
  __bf16* wb   = (__bf16*)(ws);                         // 2 MB
  __bf16* xnT  = (__bf16*)(ws + (size_t)(2  << 20));    // 8 MB
  __bf16* qTb  = (__bf16*)(ws + (size_t)(10 << 20));    // 8 MB
  __bf16* kTb  = (__bf16*)(ws + (size_t)(18 << 20));    // 8 MB
  __bf16* vbf  = (__bf16*)(ws + (size_t)(26 << 20));    // 8 MB
  __bf16* aT   = (__bf16*)(ws + (size_t)(34 << 20));    // 8 MB
  float2* psum = (float2*)(ws + (size_t)(42 << 20));    // 4 KB

  hipLaunchKernelGGL(prep_kernel, dim3(1536), dim3(256), 0, stream,
                     qw, kw, vw, pw, wb, x, psum);
  hipLaunchKernelGGL(gn_apply_kernel, dim3(32, 8, 2), dim3(256), 0, stream, x, psum, gnw, gnb, xnT);
  hipLaunchKernelGGL(gemm_qkv_kernel, dim3(8, 8, 8), dim3(256), 0, stream,
                     wb, qb, kb, vb, xnT, qTb, kTb, vbf);
  hipLaunchKernelGGL(attn_kernel, dim3(64, 8), dim3(256), 0, stream, qTb, kTb, vbf, aT);
  hipLaunchKernelGGL(gemm_proj_kernel, dim3(8, 8, 8), dim3(256), 0, stream,
                     wb + (size_t)3 * 512 * 512, pb, aT, x, out);
}

// Round 3
// 148.311 us; speedup vs baseline: 1.0077x; 1.0077x over previous
//
#include <hip/hip_runtime.h>

#define C_DIM 512
#define N_PIX 1024
#define B_DIM 8
#define NHEAD 8
#define HDIM 64
#define NGRP 8
#define CG 64
#define EPSF 1e-5f

typedef __bf16 bf16x8_t __attribute__((ext_vector_type(8)));
typedef __bf16 bf16x4_t __attribute__((ext_vector_type(4)));
typedef float  f32x4_t  __attribute__((ext_vector_type(4)));
typedef unsigned int u32x4_t __attribute__((ext_vector_type(4)));

__device__ __forceinline__ __bf16 f2b(float f) {
  unsigned int u = __builtin_bit_cast(unsigned int, f);
  u += 0x7fffu + ((u >> 16) & 1u);
  unsigned short s = (unsigned short)(u >> 16);
  return __builtin_bit_cast(__bf16, s);
}

// truncating pack: two fp32 -> packed bf16 pair (low=a, high=b); P>=0 so safe
__device__ __forceinline__ unsigned int pack_trunc(float a, float b) {
  return (__builtin_bit_cast(unsigned int, a) >> 16) |
         (__builtin_bit_cast(unsigned int, b) & 0xffff0000u);
}

__device__ __forceinline__ void async16(const void* g, void* l) {
  __builtin_amdgcn_global_load_lds((const __attribute__((address_space(1))) void*)g,
                                   (__attribute__((address_space(3))) void*)l, 16, 0, 0);
}

// ---------------- prep: weight fp32->bf16 (blocks 0..1023) + GN stats (1024..1535) ----------------
__global__ __launch_bounds__(256) void prep_kernel(
    const float* __restrict__ qw, const float* __restrict__ kw,
    const float* __restrict__ vw, const float* __restrict__ pw,
    __bf16* __restrict__ wb,
    const float* __restrict__ x, float2* __restrict__ psum)
{
  if (blockIdx.x < 1024) {
    int idx = blockIdx.x * 256 + threadIdx.x;
    int mat = idx >> 16;
    int off = (idx & 65535) * 4;
    const float* src = (mat == 0) ? qw : (mat == 1) ? kw : (mat == 2) ? vw : pw;
    float4 v = *(const float4*)(src + off);
    bf16x4_t pk;
    pk[0] = f2b(v.x); pk[1] = f2b(v.y); pk[2] = f2b(v.z); pk[3] = f2b(v.w);
    *(bf16x4_t*)(wb + mat * (512 * 512) + off) = pk;
  } else {
    const int t = blockIdx.x - 1024;
    const int s = t & 7, bg = t >> 3;
    const float* xp = x + ((size_t)bg * CG + s * 8) * N_PIX;
    float sum = 0.f, sum2 = 0.f;
#pragma unroll
    for (int it = 0; it < 8; it++) {
      float4 v = ((const float4*)xp)[it * 256 + threadIdx.x];
      sum  += v.x + v.y + v.z + v.w;
      sum2 += v.x * v.x + v.y * v.y + v.z * v.z + v.w * v.w;
    }
#pragma unroll
    for (int off = 32; off; off >>= 1) {
      sum  += __shfl_xor(sum, off, 64);
      sum2 += __shfl_xor(sum2, off, 64);
    }
    __shared__ float red[8];
    const int lane = threadIdx.x & 63, wv = threadIdx.x >> 6;
    if (lane == 0) { red[wv] = sum; red[4 + wv] = sum2; }
    __syncthreads();
    if (threadIdx.x == 0) {
      float s1 = red[0] + red[1] + red[2] + red[3];
      float s2 = red[4] + red[5] + red[6] + red[7];
      psum[bg * 8 + s] = make_float2(s1, s2);
    }
  }
}

// ---------------- GroupNorm apply + transpose -> xnT bf16 [B][N][C] ----------------
// z-split over channel halves: 512 blocks (2/CU) instead of 256 (1/CU).
__global__ __launch_bounds__(256) void gn_apply_kernel(
    const float* __restrict__ x, const float2* __restrict__ psum,
    const float* __restrict__ gw, const float* __restrict__ gb,
    __bf16* __restrict__ xnT)
{
  const int n0 = blockIdx.x * 32, b = blockIdx.y, z = blockIdx.z;
  const int tid = threadIdx.x;
  __shared__ float mu_s[8], rs_s[8];
  __shared__ __align__(16) __bf16 tile[32 * 264];

  if (tid < 8) {
    float s1 = 0.f, s2 = 0.f;
#pragma unroll
    for (int i = 0; i < 8; i++) {
      float2 p = psum[(b * 8 + tid) * 8 + i];
      s1 += p.x; s2 += p.y;
    }
    const float inv = 1.f / (float)(CG * N_PIX);
    float mu = s1 * inv;
    float var = s2 * inv - mu * mu;
    mu_s[tid] = mu;
    rs_s[tid] = rsqrtf(var + EPSF);
  }
  __syncthreads();

  const float* xb = x + (size_t)b * C_DIM * N_PIX + n0;
  const int cl = tid >> 3;
  const int nq = (tid & 7) * 4;
#pragma unroll
  for (int co = 0; co < 8; co++) {
    const int cc = co * 32 + cl;
    const int c = z * 256 + cc;
    float4 v = *(const float4*)(xb + (size_t)c * N_PIX + nq);
    const int g = c >> 6;
    const float rs = rs_s[g];
    const float a = rs * gw[c];
    const float bb = gb[c] - mu_s[g] * a;
    tile[(nq + 0) * 264 + cc] = f2b(v.x * a + bb);
    tile[(nq + 1) * 264 + cc] = f2b(v.y * a + bb);
    tile[(nq + 2) * 264 + cc] = f2b(v.z * a + bb);
    tile[(nq + 3) * 264 + cc] = f2b(v.w * a + bb);
  }
  __syncthreads();

  __bf16* dst = xnT + ((size_t)b * N_PIX + n0) * C_DIM + z * 256;
  const int l32 = tid & 31, nr = tid >> 5;
#pragma unroll
  for (int no = 0; no < 4; no++) {
    const int n = no * 8 + nr;
    const int cc = l32 * 8;
    *(bf16x8_t*)(dst + (size_t)n * C_DIM + cc) =
        *(const bf16x8_t*)(tile + n * 264 + cc);
  }
}

// ---------------- 64x128 gemm_bt core (proj): counted-vmcnt pipelined panels ----------------
// LDS k-chunk XOR-swizzle (T2, rule-21 form): global SOURCE fetches k-chunk
// (ch&3)^((row>>1)&3) into linear dest; reads use swq = (quad^((l16>>1)&3))*8.
// Breaks the 8-way bank conflict of the linear row*64B layout (all 8 bank
// windows now covered, 2 lanes each).
__device__ __forceinline__ void gemm_core_64(
    const __bf16* __restrict__ A, const __bf16* __restrict__ B,
    __bf16* As, __bf16* Bs, f32x4_t acc[2][4])
{
  const int tid  = threadIdx.x;
  const int lane = tid & 63;
  const int wv   = tid >> 6;
  const int quad = lane >> 4;
  const int l16  = lane & 15;
  const int wm = (wv >> 1) * 32;
  const int wn = (wv & 1) * 64;
  const int swq = (quad ^ ((l16 >> 1) & 3)) * 8;   // swizzled k-chunk for fragment reads

  f32x4_t zero = {0.f, 0.f, 0.f, 0.f};
#pragma unroll
  for (int i = 0; i < 2; i++)
#pragma unroll
    for (int j = 0; j < 4; j++) acc[i][j] = zero;

  const int chA  = wv * 64 + lane;
  const int rA = chA >> 2;
  const int kA = ((chA & 3) ^ ((rA >> 1) & 3)) * 8;   // inverse-swizzled source k-chunk
  const int chB0 = wv * 64 + lane, chB1 = 256 + wv * 64 + lane;
  const int rB0 = chB0 >> 2, kB0 = ((chB0 & 3) ^ ((rB0 >> 1) & 3)) * 8;
  const int rB1 = chB1 >> 2, kB1 = ((chB1 & 3) ^ ((rB1 >> 1) & 3)) * 8;

  // prologue: stage panel 0 into buf 0 (left in flight; waited in phase 0)
  async16(A + (size_t)rA * 512 + kA,  As + (wv * 64) * 8);
  async16(B + (size_t)rB0 * 512 + kB0, Bs + (wv * 64) * 8);
  async16(B + (size_t)rB1 * 512 + kB1, Bs + (256 + wv * 64) * 8);

  for (int kt2 = 0; kt2 < 8; kt2++) {
#pragma unroll
    for (int pp = 0; pp < 2; pp++) {
      const int pi = kt2 * 2 + pp;
      if (pi < 15) {
        const int kc = (pi + 1) * 32;
        const int nb = (pi + 1) & 1;
        async16(A + (size_t)rA * 512 + kc + kA,  As + nb * 2048 + (wv * 64) * 8);
        async16(B + (size_t)rB0 * 512 + kc + kB0, Bs + nb * 4096 + (wv * 64) * 8);
        async16(B + (size_t)rB1 * 512 + kc + kB1, Bs + nb * 4096 + (256 + wv * 64) * 8);
        // wait only for panel pi's 3 loads; pi+1's 3 remain in flight
        asm volatile("s_waitcnt vmcnt(3)" ::: "memory");
      } else {
        asm volatile("s_waitcnt vmcnt(0)" ::: "memory");
      }
      __builtin_amdgcn_s_barrier();
      __builtin_amdgcn_sched_barrier(0);
      bf16x8_t af[2], bfr[4];
#pragma unroll
      for (int i = 0; i < 2; i++)
        af[i] = *(const bf16x8_t*)(As + pp * 2048 + (wm + i * 16 + l16) * 32 + swq);
#pragma unroll
      for (int j = 0; j < 4; j++)
        bfr[j] = *(const bf16x8_t*)(Bs + pp * 4096 + (wn + j * 16 + l16) * 32 + swq);
      __builtin_amdgcn_s_setprio(1);
#pragma unroll
      for (int i = 0; i < 2; i++)
#pragma unroll
        for (int j = 0; j < 4; j++)
          acc[i][j] = __builtin_amdgcn_mfma_f32_16x16x32_bf16(af[i], bfr[j], acc[i][j], 0, 0, 0);
      __builtin_amdgcn_s_setprio(0);
      __builtin_amdgcn_sched_barrier(0);
      __builtin_amdgcn_s_barrier();   // buf[pi&1] free for reuse after this
    }
  }
}

// ---------------- FUSED QKV gemm: one block computes Q,K,V 64x128 tiles ----------------
// grid (8=b, 8=n, 8=m). B (xnT tile) staged ONCE per panel, 24 MFMA/phase.
// Counted-vmcnt pipeline + T2 source-side LDS swizzle (see gemm_core_64 comment).
__global__ __launch_bounds__(256, 2) void gemm_qkv_kernel(
    const __bf16* __restrict__ wqkv, const float* __restrict__ qb,
    const float* __restrict__ kb, const float* __restrict__ vb,
    const __bf16* __restrict__ xnT,
    __bf16* __restrict__ qT, __bf16* __restrict__ kT, __bf16* __restrict__ vbuf)
{
  // 40 KB: Aq(0) Ak(4096) Av(8192) each 2 panels x 2048; Bs(12288) 2 panels x 4096.
  __shared__ __align__(16) __bf16 smem[20480];
  __bf16* Bs = smem + 12288;
  const int b = blockIdx.x;
  const int n0 = blockIdx.y * 128;
  const int m0 = blockIdx.z * 64;
  const __bf16* Aq = wqkv + (size_t)m0 * 512;
  const __bf16* Ak = Aq + 512 * 512;
  const __bf16* Av = Ak + 512 * 512;
  const __bf16* Bx = xnT + ((size_t)b * N_PIX + n0) * 512;

  const int tid = threadIdx.x, lane = tid & 63, wv = tid >> 6;
  const int quad = lane >> 4, l16 = lane & 15;
  const int wm = (wv >> 1) * 32, wn = (wv & 1) * 64;
  const int swq = (quad ^ ((l16 >> 1) & 3)) * 8;   // swizzled k-chunk for fragment reads

  const f32x4_t zero = {0.f, 0.f, 0.f, 0.f};
  f32x4_t acc[3][2][4];
#pragma unroll
  for (int m = 0; m < 3; m++)
#pragma unroll
    for (int i = 0; i < 2; i++)
#pragma unroll
      for (int j = 0; j < 4; j++) acc[m][i][j] = zero;

  const int chA = wv * 64 + lane;
  const int rA = chA >> 2;
  const int kA = ((chA & 3) ^ ((rA >> 1) & 3)) * 8;   // inverse-swizzled source k-chunk
  const int chB0 = wv * 64 + lane, chB1 = 256 + wv * 64 + lane;
  const int rB0 = chB0 >> 2, kB0 = ((chB0 & 3) ^ ((rB0 >> 1) & 3)) * 8;
  const int rB1 = chB1 >> 2, kB1 = ((chB1 & 3) ^ ((rB1 >> 1) & 3)) * 8;

  // prologue: stage panel 0 into buf 0
  async16(Aq + (size_t)rA * 512 + kA, smem + (wv * 64) * 8);
  async16(Ak + (size_t)rA * 512 + kA, smem + 4096 + (wv * 64) * 8);
  async16(Av + (size_t)rA * 512 + kA, smem + 8192 + (wv * 64) * 8);
  async16(Bx + (size_t)rB0 * 512 + kB0, Bs + (wv * 64) * 8);
  async16(Bx + (size_t)rB1 * 512 + kB1, Bs + (256 + wv * 64) * 8);

  for (int kt2 = 0; kt2 < 8; kt2++) {
#pragma unroll
    for (int pp = 0; pp < 2; pp++) {
      const int pi = kt2 * 2 + pp;
      if (pi < 15) {
        const int kc = (pi + 1) * 32;
        const int nb = (pi + 1) & 1;
        async16(Aq + (size_t)rA * 512 + kc + kA, smem + nb * 2048 + (wv * 64) * 8);
        async16(Ak + (size_t)rA * 512 + kc + kA, smem + 4096 + nb * 2048 + (wv * 64) * 8);
        async16(Av + (size_t)rA * 512 + kc + kA, smem + 8192 + nb * 2048 + (wv * 64) * 8);
        async16(Bx + (size_t)rB0 * 512 + kc + kB0, Bs + nb * 4096 + (wv * 64) * 8);
        async16(Bx + (size_t)rB1 * 512 + kc + kB1, Bs + nb * 4096 + (256 + wv * 64) * 8);
        // wait only for panel pi's 5 loads; pi+1's 5 remain in flight
        asm volatile("s_waitcnt vmcnt(5)" ::: "memory");
      } else {
        asm volatile("s_waitcnt vmcnt(0)" ::: "memory");
      }
      __builtin_amdgcn_s_barrier();
      __builtin_amdgcn_sched_barrier(0);
      bf16x8_t bfr[4];
#pragma unroll
      for (int j = 0; j < 4; j++)
        bfr[j] = *(const bf16x8_t*)(Bs + pp * 4096 + (wn + j * 16 + l16) * 32 + swq);
#pragma unroll
      for (int m = 0; m < 3; m++) {
        bf16x8_t af[2];
#pragma unroll
        for (int i = 0; i < 2; i++)
          af[i] = *(const bf16x8_t*)(smem + m * 4096 + pp * 2048 + (wm + i * 16 + l16) * 32 + swq);
        __builtin_amdgcn_s_setprio(1);
#pragma unroll
        for (int i = 0; i < 2; i++)
#pragma unroll
          for (int j = 0; j < 4; j++)
            acc[m][i][j] = __builtin_amdgcn_mfma_f32_16x16x32_bf16(af[i], bfr[j], acc[m][i][j], 0, 0, 0);
        __builtin_amdgcn_s_setprio(0);
      }
      __builtin_amdgcn_sched_barrier(0);
      __builtin_amdgcn_s_barrier();   // buffers free for next phase's loads
    }
  }

  // ---- epilogues (sequential, reuse smem; all coalesced via LDS transpose) ----
  const float qscale = 0.125f * 1.44269504f;   // HD^-0.5 * log2(e), folded into Q
#pragma unroll
  for (int mat = 0; mat < 2; mat++) {
    const float* bias = (mat == 0) ? qb : kb;
    const float sc = (mat == 0) ? qscale : 1.0f;
    __bf16* dst = (mat == 0) ? qT : kT;
#pragma unroll
    for (int i = 0; i < 2; i++) {
      const int crow = wm + i * 16 + quad * 4;
      const int o = m0 + crow;
      float b0 = bias[o], b1 = bias[o + 1], b2 = bias[o + 2], b3 = bias[o + 3];
#pragma unroll
      for (int j = 0; j < 4; j++) {
        const int nl = wn + j * 16 + l16;
        bf16x4_t pk;
        pk[0] = f2b((acc[mat][i][j][0] + b0) * sc);
        pk[1] = f2b((acc[mat][i][j][1] + b1) * sc);
        pk[2] = f2b((acc[mat][i][j][2] + b2) * sc);
        pk[3] = f2b((acc[mat][i][j][3] + b3) * sc);
        *(bf16x4_t*)(smem + nl * 72 + crow) = pk;
      }
    }
    __syncthreads();
#pragma unroll
    for (int it = 0; it < 4; it++) {
      const int n = it * 32 + (tid >> 3);
      const int c = (tid & 7) * 8;
      *(bf16x8_t*)(dst + ((size_t)b * N_PIX + n0 + n) * 512 + m0 + c) =
          *(const bf16x8_t*)(smem + n * 72 + c);
    }
    __syncthreads();
  }
  // V: [c][n] layout via stride-132 transpose
#pragma unroll
  for (int i = 0; i < 2; i++) {
    const int crow = wm + i * 16 + quad * 4;
    const int o = m0 + crow;
    float b0 = vb[o], b1 = vb[o + 1], b2 = vb[o + 2], b3 = vb[o + 3];
#pragma unroll
    for (int j = 0; j < 4; j++) {
      const int nl = wn + j * 16 + l16;
      smem[(crow + 0) * 132 + nl] = f2b(acc[2][i][j][0] + b0);
      smem[(crow + 1) * 132 + nl] = f2b(acc[2][i][j][1] + b1);
      smem[(crow + 2) * 132 + nl] = f2b(acc[2][i][j][2] + b2);
      smem[(crow + 3) * 132 + nl] = f2b(acc[2][i][j][3] + b3);
    }
  }
  __syncthreads();
  {
    const int c = tid >> 2;
    const int nch = (tid & 3) * 32;
    __bf16* vd = vbuf + ((size_t)b * 512 + m0 + c) * N_PIX + n0 + nch;
#pragma unroll
    for (int k = 0; k < 4; k++)
      *(bf16x8_t*)(vd + k * 8) = *(const bf16x8_t*)(smem + c * 132 + nch + k * 8);
  }
}

// ---------------- attention: 32 q/wave, permuted V, double-buffered, LDS-transposed out ----------------
// Raw barriers with lgkm-only drain: the 2-ahead K/V global prefetch stays in flight.
__global__ __launch_bounds__(256, 2) void attn_kernel(
    const __bf16* __restrict__ qT, const __bf16* __restrict__ kT,
    const __bf16* __restrict__ vbuf, __bf16* __restrict__ aT)
{
  __shared__ __align__(16) __bf16 Ks[2][64 * 72];
  __shared__ __align__(16) __bf16 Vp[2][64 * 72];
  const int bh = blockIdx.x;
  const int b = bh >> 3, head = bh & 7;
  const int n0 = blockIdx.y * 128;
  const int tid = threadIdx.x, lane = tid & 63, wv = tid >> 6;
  const int quad = lane >> 4, l16 = lane & 15;

  bf16x8_t qf[2][2];
#pragma unroll
  for (int qt = 0; qt < 2; qt++) {
    const __bf16* qp = qT + ((size_t)b * N_PIX + n0 + wv * 32 + qt * 16 + l16) * 512 + head * 64;
    qf[qt][0] = *(const bf16x8_t*)(qp + quad * 8);
    qf[qt][1] = *(const bf16x8_t*)(qp + 32 + quad * 8);
  }

  const __bf16* kp = kT + ((size_t)b * N_PIX) * 512 + head * 64;
  const __bf16* vp = vbuf + ((size_t)b * 512 + head * 64) * N_PIX;

  const int srow = tid >> 2, scol = (tid & 3) * 16;
  const int pr0 = scol >> 5, hh0 = (scol >> 4) & 1;
  const int pos0 = pr0 * 32 + ((scol >> 2) & 3) * 8 + hh0 * 4;
  const int mc1 = scol + 8;
  const int pr1 = mc1 >> 5, hh1 = (mc1 >> 4) & 1;
  const int pos1 = pr1 * 32 + ((mc1 >> 2) & 3) * 8 + hh1 * 4;

  bf16x8_t kreg0 = *(const bf16x8_t*)(kp + (size_t)srow * 512 + scol);
  bf16x8_t kreg1 = *(const bf16x8_t*)(kp + (size_t)srow * 512 + scol + 8);
  bf16x8_t vreg0 = *(const bf16x8_t*)(vp + (size_t)srow * N_PIX + scol);
  bf16x8_t vreg1 = *(const bf16x8_t*)(vp + (size_t)srow * N_PIX + scol + 8);
  {
    *(bf16x8_t*)(Ks[0] + srow * 72 + scol)     = kreg0;
    *(bf16x8_t*)(Ks[0] + srow * 72 + scol + 8) = kreg1;
    bf16x4_t lo, hi;
#pragma unroll
    for (int r = 0; r < 4; r++) { lo[r] = vreg0[r]; hi[r] = vreg0[4 + r]; }
    *(bf16x4_t*)(Vp[0] + srow * 72 + pos0)     = lo;
    *(bf16x4_t*)(Vp[0] + srow * 72 + pos0 + 8) = hi;
#pragma unroll
    for (int r = 0; r < 4; r++) { lo[r] = vreg1[r]; hi[r] = vreg1[4 + r]; }
    *(bf16x4_t*)(Vp[0] + srow * 72 + pos1)     = lo;
    *(bf16x4_t*)(Vp[0] + srow * 72 + pos1 + 8) = hi;
  }
  kreg0 = *(const bf16x8_t*)(kp + (size_t)(64 + srow) * 512 + scol);
  kreg1 = *(const bf16x8_t*)(kp + (size_t)(64 + srow) * 512 + scol + 8);
  vreg0 = *(const bf16x8_t*)(vp + (size_t)srow * N_PIX + 64 + scol);
  vreg1 = *(const bf16x8_t*)(vp + (size_t)srow * N_PIX + 64 + scol + 8);
  // LDS-write visibility only; tile-1 global prefetch stays in flight
  asm volatile("s_waitcnt lgkmcnt(0)" ::: "memory");
  __builtin_amdgcn_s_barrier();
  __builtin_amdgcn_sched_barrier(0);

  const f32x4_t zero = {0.f, 0.f, 0.f, 0.f};
  f32x4_t oacc[2][4];
#pragma unroll
  for (int qt = 0; qt < 2; qt++)
#pragma unroll
    for (int jc = 0; jc < 4; jc++) oacc[qt][jc] = zero;
  f32x4_t lsum4[2] = {zero, zero};

  for (int mt = 0; mt < 16; mt++) {
    const int cur = mt & 1, nxt = cur ^ 1;
    const __bf16* Kc = Ks[cur];
    const __bf16* Vc = Vp[cur];

    f32x4_t sacc[2][4];
    __builtin_amdgcn_s_setprio(1);
#pragma unroll
    for (int mb = 0; mb < 4; mb++) {
      bf16x8_t kf0 = *(const bf16x8_t*)(Kc + (mb * 16 + l16) * 72 + quad * 8);
      bf16x8_t kf1 = *(const bf16x8_t*)(Kc + (mb * 16 + l16) * 72 + 32 + quad * 8);
#pragma unroll
      for (int qt = 0; qt < 2; qt++) {
        f32x4_t s = zero;
        s = __builtin_amdgcn_mfma_f32_16x16x32_bf16(kf0, qf[qt][0], s, 0, 0, 0);
        s = __builtin_amdgcn_mfma_f32_16x16x32_bf16(kf1, qf[qt][1], s, 0, 0, 0);
        sacc[qt][mb] = s;
      }
    }
    __builtin_amdgcn_s_setprio(0);

    bf16x8_t pf[2][2];
#pragma unroll
    for (int qt = 0; qt < 2; qt++) {
      float p[4][4];
#pragma unroll
      for (int mb = 0; mb < 4; mb++)
#pragma unroll
        for (int r = 0; r < 4; r++) {
          p[mb][r] = __builtin_amdgcn_exp2f(sacc[qt][mb][r]);
          lsum4[qt][r] += p[mb][r];
        }
#pragma unroll
      for (int pr = 0; pr < 2; pr++) {
        u32x4_t u;
        u[0] = pack_trunc(p[2 * pr][0],     p[2 * pr][1]);
        u[1] = pack_trunc(p[2 * pr][2],     p[2 * pr][3]);
        u[2] = pack_trunc(p[2 * pr + 1][0], p[2 * pr + 1][1]);
        u[3] = pack_trunc(p[2 * pr + 1][2], p[2 * pr + 1][3]);
        pf[qt][pr] = __builtin_bit_cast(bf16x8_t, u);
      }
    }

    __builtin_amdgcn_s_setprio(1);
#pragma unroll
    for (int jc = 0; jc < 4; jc++) {
      const int vrow = (jc * 16 + l16) * 72;
#pragma unroll
      for (int pr = 0; pr < 2; pr++) {
        bf16x8_t vf = *(const bf16x8_t*)(Vc + vrow + pr * 32 + quad * 8);
#pragma unroll
        for (int qt = 0; qt < 2; qt++)
          oacc[qt][jc] = __builtin_amdgcn_mfma_f32_16x16x32_bf16(vf, pf[qt][pr], oacc[qt][jc], 0, 0, 0);
      }
    }
    __builtin_amdgcn_s_setprio(0);

    if (mt < 15) {
      *(bf16x8_t*)(Ks[nxt] + srow * 72 + scol)     = kreg0;
      *(bf16x8_t*)(Ks[nxt] + srow * 72 + scol + 8) = kreg1;
      bf16x4_t lo, hi;
#pragma unroll
      for (int r = 0; r < 4; r++) { lo[r] = vreg0[r]; hi[r] = vreg0[4 + r]; }
      *(bf16x4_t*)(Vp[nxt] + srow * 72 + pos0)     = lo;
      *(bf16x4_t*)(Vp[nxt] + srow * 72 + pos0 + 8) = hi;
#pragma unroll
      for (int r = 0; r < 4; r++) { lo[r] = vreg1[r]; hi[r] = vreg1[4 + r]; }
      *(bf16x4_t*)(Vp[nxt] + srow * 72 + pos1)     = lo;
      *(bf16x4_t*)(Vp[nxt] + srow * 72 + pos1 + 8) = hi;
      if (mt < 14) {
        kreg0 = *(const bf16x8_t*)(kp + (size_t)((mt + 2) * 64 + srow) * 512 + scol);
        kreg1 = *(const bf16x8_t*)(kp + (size_t)((mt + 2) * 64 + srow) * 512 + scol + 8);
        vreg0 = *(const bf16x8_t*)(vp + (size_t)srow * N_PIX + (mt + 2) * 64 + scol);
        vreg1 = *(const bf16x8_t*)(vp + (size_t)srow * N_PIX + (mt + 2) * 64 + scol + 8);
      }
      // LDS-write visibility only; next-tile global prefetch stays in flight
      asm volatile("s_waitcnt lgkmcnt(0)" ::: "memory");
      __builtin_amdgcn_s_barrier();
      __builtin_amdgcn_sched_barrier(0);
    }
  }

  // O epilogue: normalize, transpose through LDS (reuse Ks), coalesced stores
  __syncthreads();
  __bf16* Tr = &Ks[0][0];
#pragma unroll
  for (int qt = 0; qt < 2; qt++) {
    float lsum = lsum4[qt][0] + lsum4[qt][1] + lsum4[qt][2] + lsum4[qt][3];
    lsum += __shfl_xor(lsum, 16, 64);
    lsum += __shfl_xor(lsum, 32, 64);
    const float inv = 1.f / lsum;
    const int nl = wv * 32 + qt * 16 + l16;
#pragma unroll
    for (int jc = 0; jc < 4; jc++) {
      bf16x4_t o4;
#pragma unroll
      for (int r = 0; r < 4; r++) o4[r] = f2b(oacc[qt][jc][r] * inv);
      *(bf16x4_t*)(Tr + nl * 72 + jc * 16 + quad * 4) = o4;
    }
  }
  __syncthreads();
#pragma unroll
  for (int it = 0; it < 4; it++) {
    const int n = it * 32 + (tid >> 3);
    const int c = (tid & 7) * 8;
    *(bf16x8_t*)(aT + ((size_t)b * N_PIX + n0 + n) * 512 + head * 64 + c) =
        *(const bf16x8_t*)(Tr + n * 72 + c);
  }
}

// ---------------- proj gemm + bias + residual: 64x128 tiles, grid (8=b, 8=n, 8=m) ----------------
__global__ __launch_bounds__(256, 4) void gemm_proj_kernel(
    const __bf16* __restrict__ wp, const float* __restrict__ pb,
    const __bf16* __restrict__ aT, const float* __restrict__ x,
    float* __restrict__ out)
{
  __shared__ __align__(16) __bf16 smem[12288];
  __bf16* As = smem;
  __bf16* Bs = smem + 4096;
  const int b = blockIdx.x;
  const int n0 = blockIdx.y * 128;
  const int m0 = blockIdx.z * 64;
  const __bf16* A = wp + (size_t)m0 * 512;
  const __bf16* B = aT + ((size_t)b * N_PIX + n0) * 512;
  f32x4_t acc[2][4];
  gemm_core_64(A, B, As, Bs, acc);
  const int tid = threadIdx.x, lane = tid & 63, wv = tid >> 6;
  const int quad = lane >> 4, l16 = lane & 15;
  const int wm = (wv >> 1) * 32, wn = (wv & 1) * 64;
#pragma unroll
  for (int i = 0; i < 2; i++) {
    const int o = m0 + wm + i * 16 + quad * 4;
#pragma unroll
    for (int j = 0; j < 4; j++) {
      const int n = n0 + wn + j * 16 + l16;
#pragma unroll
      for (int r = 0; r < 4; r++) {
        size_t idx = ((size_t)b * 512 + o + r) * N_PIX + n;
        out[idx] = acc[i][j][r] + pb[o + r] + x[idx];
      }
    }
  }
}

extern "C" void kernel_launch(void* const* d_in, const int* in_sizes, int n_in,
                              void* d_out, int out_size, void* d_ws, size_t ws_size,
                              hipStream_t stream)
{
  (void)in_sizes; (void)n_in; (void)out_size; (void)ws_size;
  const float* x   = (const float*)d_in[0];
  const float* gnw = (const float*)d_in[1];
  const float* gnb = (const float*)d_in[2];
  const float* qw  = (const float*)d_in[3];
  const float* qb  = (const float*)d_in[4];
  const float* kw  = (const float*)d_in[5];
  const float* kb  = (const float*)d_in[6];
  const float* vw  = (const float*)d_in[7];
  const float* vb  = (const float*)d_in[8];
  const float* pw  = (const float*)d_in[9];
  const float* pb  = (const float*)d_in[10];
  float* out = (float*)d_out;

  char* ws = (char*)d_ws;
  __bf16* wb   = (__bf16*)(ws);                         // 2 MB
  __bf16* xnT  = (__bf16*)(ws + (size_t)(2  << 20));    // 8 MB
  __bf16* qTb  = (__bf16*)(ws + (size_t)(10 << 20));    // 8 MB
  __bf16* kTb  = (__bf16*)(ws + (size_t)(18 << 20));    // 8 MB
  __bf16* vbf  = (__bf16*)(ws + (size_t)(26 << 20));    // 8 MB
  __bf16* aT   = (__bf16*)(ws + (size_t)(34 << 20));    // 8 MB
  float2* psum = (float2*)(ws + (size_t)(42 << 20));    // 4 KB

  hipLaunchKernelGGL(prep_kernel, dim3(1536), dim3(256), 0, stream,
                     qw, kw, vw, pw, wb, x, psum);
  hipLaunchKernelGGL(gn_apply_kernel, dim3(32, 8, 2), dim3(256), 0, stream, x, psum, gnw, gnb, xnT);
  hipLaunchKernelGGL(gemm_qkv_kernel, dim3(8, 8, 8), dim3(256), 0, stream,
                     wb, qb, kb, vb, xnT, qTb, kTb, vbf);
  hipLaunchKernelGGL(attn_kernel, dim3(64, 8), dim3(256), 0, stream, qTb, kTb, vbf, aT);
  hipLaunchKernelGGL(gemm_proj_kernel, dim3(8, 8, 8), dim3(256), 0, stream,
                     wb + (size_t)3 * 512 * 512, pb, aT, x, out);
}

// Round 5
// 148.111 us; speedup vs baseline: 1.0090x; 1.0013x over previous
//
#include <hip/hip_runtime.h>

#define C_DIM 512
#define N_PIX 1024
#define B_DIM 8
#define NHEAD 8
#define HDIM 64
#define NGRP 8
#define CG 64
#define EPSF 1e-5f

typedef __bf16 bf16x8_t __attribute__((ext_vector_type(8)));
typedef __bf16 bf16x4_t __attribute__((ext_vector_type(4)));
typedef float  f32x4_t  __attribute__((ext_vector_type(4)));
typedef unsigned int u32x4_t __attribute__((ext_vector_type(4)));

__device__ __forceinline__ __bf16 f2b(float f) {
  unsigned int u = __builtin_bit_cast(unsigned int, f);
  u += 0x7fffu + ((u >> 16) & 1u);
  unsigned short s = (unsigned short)(u >> 16);
  return __builtin_bit_cast(__bf16, s);
}

// truncating pack: two fp32 -> packed bf16 pair (low=a, high=b); P>=0 so safe
__device__ __forceinline__ unsigned int pack_trunc(float a, float b) {
  return (__builtin_bit_cast(unsigned int, a) >> 16) |
         (__builtin_bit_cast(unsigned int, b) & 0xffff0000u);
}

__device__ __forceinline__ void async16(const void* g, void* l) {
  __builtin_amdgcn_global_load_lds((const __attribute__((address_space(1))) void*)g,
                                   (__attribute__((address_space(3))) void*)l, 16, 0, 0);
}

// ---------------- prep: weight fp32->bf16 (blocks 0..1023) + GN stats (1024..1535) ----------------
__global__ __launch_bounds__(256) void prep_kernel(
    const float* __restrict__ qw, const float* __restrict__ kw,
    const float* __restrict__ vw, const float* __restrict__ pw,
    __bf16* __restrict__ wb,
    const float* __restrict__ x, float2* __restrict__ psum)
{
  if (blockIdx.x < 1024) {
    int idx = blockIdx.x * 256 + threadIdx.x;
    int mat = idx >> 16;
    int off = (idx & 65535) * 4;
    const float* src = (mat == 0) ? qw : (mat == 1) ? kw : (mat == 2) ? vw : pw;
    float4 v = *(const float4*)(src + off);
    bf16x4_t pk;
    pk[0] = f2b(v.x); pk[1] = f2b(v.y); pk[2] = f2b(v.z); pk[3] = f2b(v.w);
    *(bf16x4_t*)(wb + mat * (512 * 512) + off) = pk;
  } else {
    const int t = blockIdx.x - 1024;
    const int s = t & 7, bg = t >> 3;
    const float* xp = x + ((size_t)bg * CG + s * 8) * N_PIX;
    float sum = 0.f, sum2 = 0.f;
#pragma unroll
    for (int it = 0; it < 8; it++) {
      float4 v = ((const float4*)xp)[it * 256 + threadIdx.x];
      sum  += v.x + v.y + v.z + v.w;
      sum2 += v.x * v.x + v.y * v.y + v.z * v.z + v.w * v.w;
    }
#pragma unroll
    for (int off = 32; off; off >>= 1) {
      sum  += __shfl_xor(sum, off, 64);
      sum2 += __shfl_xor(sum2, off, 64);
    }
    __shared__ float red[8];
    const int lane = threadIdx.x & 63, wv = threadIdx.x >> 6;
    if (lane == 0) { red[wv] = sum; red[4 + wv] = sum2; }
    __syncthreads();
    if (threadIdx.x == 0) {
      float s1 = red[0] + red[1] + red[2] + red[3];
      float s2 = red[4] + red[5] + red[6] + red[7];
      psum[bg * 8 + s] = make_float2(s1, s2);
    }
  }
}

// ---------------- GroupNorm apply + transpose -> xnT bf16 [B][N][C] ----------------
// z-split over channel halves: 512 blocks (2/CU).
__global__ __launch_bounds__(256) void gn_apply_kernel(
    const float* __restrict__ x, const float2* __restrict__ psum,
    const float* __restrict__ gw, const float* __restrict__ gb,
    __bf16* __restrict__ xnT)
{
  const int n0 = blockIdx.x * 32, b = blockIdx.y, z = blockIdx.z;
  const int tid = threadIdx.x;
  __shared__ float mu_s[8], rs_s[8];
  __shared__ __align__(16) __bf16 tile[32 * 264];

  if (tid < 8) {
    float s1 = 0.f, s2 = 0.f;
#pragma unroll
    for (int i = 0; i < 8; i++) {
      float2 p = psum[(b * 8 + tid) * 8 + i];
      s1 += p.x; s2 += p.y;
    }
    const float inv = 1.f / (float)(CG * N_PIX);
    float mu = s1 * inv;
    float var = s2 * inv - mu * mu;
    mu_s[tid] = mu;
    rs_s[tid] = rsqrtf(var + EPSF);
  }
  __syncthreads();

  const float* xb = x + (size_t)b * C_DIM * N_PIX + n0;
  const int cl = tid >> 3;
  const int nq = (tid & 7) * 4;
#pragma unroll
  for (int co = 0; co < 8; co++) {
    const int cc = co * 32 + cl;
    const int c = z * 256 + cc;
    float4 v = *(const float4*)(xb + (size_t)c * N_PIX + nq);
    const int g = c >> 6;
    const float rs = rs_s[g];
    const float a = rs * gw[c];
    const float bb = gb[c] - mu_s[g] * a;
    tile[(nq + 0) * 264 + cc] = f2b(v.x * a + bb);
    tile[(nq + 1) * 264 + cc] = f2b(v.y * a + bb);
    tile[(nq + 2) * 264 + cc] = f2b(v.z * a + bb);
    tile[(nq + 3) * 264 + cc] = f2b(v.w * a + bb);
  }
  __syncthreads();

  __bf16* dst = xnT + ((size_t)b * N_PIX + n0) * C_DIM + z * 256;
  const int l32 = tid & 31, nr = tid >> 5;
#pragma unroll
  for (int no = 0; no < 4; no++) {
    const int n = no * 8 + nr;
    const int cc = l32 * 8;
    *(bf16x8_t*)(dst + (size_t)n * C_DIM + cc) =
        *(const bf16x8_t*)(tile + n * 264 + cc);
  }
}

// ---------------- 64x128 gemm_bt core (proj): triple-buffered panel pipeline ----------------
// Panel pi in [0,16) = 32 K-cols; buffer pi%3 (3 buffers = 36 KB). Iteration p stages
// panel p+2 into buffer (p+2)%3 (freed at p-1's trailing barrier), then waits
// vmcnt(6): panel p landed, panels p+1/p+2 (6 loads) stay in flight across BOTH
// barriers -> ~2 phases (~400-500 cyc) of latency cover. T2 source-side swizzle kept.
__device__ __forceinline__ void gemm_core_64(
    const __bf16* __restrict__ A, const __bf16* __restrict__ B,
    __bf16* smem, f32x4_t acc[2][4])
{
  const int tid  = threadIdx.x;
  const int lane = tid & 63;
  const int wv   = tid >> 6;
  const int quad = lane >> 4;
  const int l16  = lane & 15;
  const int wm = (wv >> 1) * 32;
  const int wn = (wv & 1) * 64;
  const int swq = (quad ^ ((l16 >> 1) & 3)) * 8;   // swizzled k-chunk for fragment reads

  f32x4_t zero = {0.f, 0.f, 0.f, 0.f};
#pragma unroll
  for (int i = 0; i < 2; i++)
#pragma unroll
    for (int j = 0; j < 4; j++) acc[i][j] = zero;

  const int chA  = wv * 64 + lane;
  const int rA = chA >> 2;
  const int kA = ((chA & 3) ^ ((rA >> 1) & 3)) * 8;   // inverse-swizzled source k-chunk
  const int chB0 = wv * 64 + lane, chB1 = 256 + wv * 64 + lane;
  const int rB0 = chB0 >> 2, kB0 = ((chB0 & 3) ^ ((rB0 >> 1) & 3)) * 8;
  const int rB1 = chB1 >> 2, kB1 = ((chB1 & 3) ^ ((rB1 >> 1) & 3)) * 8;

  // buffer q layout (bf16 units): base q*6144; A panel at +0 (2048), B panel at +2048 (4096)
  auto STAGE = [&](int p) {
    const int kc = p * 32;
    __bf16* base = smem + (p % 3) * 6144;
    async16(A + (size_t)rA * 512 + kc + kA,  base + (wv * 64) * 8);
    async16(B + (size_t)rB0 * 512 + kc + kB0, base + 2048 + (wv * 64) * 8);
    async16(B + (size_t)rB1 * 512 + kc + kB1, base + 2048 + (256 + wv * 64) * 8);
  };

  STAGE(0); STAGE(1);

#pragma unroll
  for (int p = 0; p < 16; p++) {
    if (p <= 13) {
      STAGE(p + 2);
      asm volatile("s_waitcnt vmcnt(6)" ::: "memory");
    } else if (p == 14) {
      asm volatile("s_waitcnt vmcnt(3)" ::: "memory");
    } else {
      asm volatile("s_waitcnt vmcnt(0)" ::: "memory");
    }
    __builtin_amdgcn_s_barrier();
    __builtin_amdgcn_sched_barrier(0);
    const __bf16* base = smem + (p % 3) * 6144;
    bf16x8_t af[2], bfr[4];
#pragma unroll
    for (int i = 0; i < 2; i++)
      af[i] = *(const bf16x8_t*)(base + (wm + i * 16 + l16) * 32 + swq);
#pragma unroll
    for (int j = 0; j < 4; j++)
      bfr[j] = *(const bf16x8_t*)(base + 2048 + (wn + j * 16 + l16) * 32 + swq);
    __builtin_amdgcn_s_setprio(1);
#pragma unroll
    for (int i = 0; i < 2; i++)
#pragma unroll
      for (int j = 0; j < 4; j++)
        acc[i][j] = __builtin_amdgcn_mfma_f32_16x16x32_bf16(af[i], bfr[j], acc[i][j], 0, 0, 0);
    __builtin_amdgcn_s_setprio(0);
    __builtin_amdgcn_sched_barrier(0);
    __builtin_amdgcn_s_barrier();   // buffer p%3 free for reuse
  }
}

// ---------------- FUSED QKV gemm: one block computes Q,K,V 64x128 tiles ----------------
// grid (8=b, 8=n, 8=m). Triple-buffered panel pipeline, 5 loads/panel, 24 MFMA/phase.
// Steady state: 10 loads (2 panels) in flight across both barriers.
__global__ __launch_bounds__(256, 2) void gemm_qkv_kernel(
    const __bf16* __restrict__ wqkv, const float* __restrict__ qb,
    const float* __restrict__ kb, const float* __restrict__ vb,
    const __bf16* __restrict__ xnT,
    __bf16* __restrict__ qT, __bf16* __restrict__ kT, __bf16* __restrict__ vbuf)
{
  // 60 KB: 3 buffers x 10240 bf16 (Aq +0, Ak +2048, Av +4096, B +6144..10239)
  __shared__ __align__(16) __bf16 smem[30720];
  const int b = blockIdx.x;
  const int n0 = blockIdx.y * 128;
  const int m0 = blockIdx.z * 64;
  const __bf16* Aq = wqkv + (size_t)m0 * 512;
  const __bf16* Ak = Aq + 512 * 512;
  const __bf16* Av = Ak + 512 * 512;
  const __bf16* Bx = xnT + ((size_t)b * N_PIX + n0) * 512;

  const int tid = threadIdx.x, lane = tid & 63, wv = tid >> 6;
  const int quad = lane >> 4, l16 = lane & 15;
  const int wm = (wv >> 1) * 32, wn = (wv & 1) * 64;
  const int swq = (quad ^ ((l16 >> 1) & 3)) * 8;   // swizzled k-chunk for fragment reads

  const f32x4_t zero = {0.f, 0.f, 0.f, 0.f};
  f32x4_t acc[3][2][4];
#pragma unroll
  for (int m = 0; m < 3; m++)
#pragma unroll
    for (int i = 0; i < 2; i++)
#pragma unroll
      for (int j = 0; j < 4; j++) acc[m][i][j] = zero;

  const int chA = wv * 64 + lane;
  const int rA = chA >> 2;
  const int kA = ((chA & 3) ^ ((rA >> 1) & 3)) * 8;   // inverse-swizzled source k-chunk
  const int chB0 = wv * 64 + lane, chB1 = 256 + wv * 64 + lane;
  const int rB0 = chB0 >> 2, kB0 = ((chB0 & 3) ^ ((rB0 >> 1) & 3)) * 8;
  const int rB1 = chB1 >> 2, kB1 = ((chB1 & 3) ^ ((rB1 >> 1) & 3)) * 8;

  auto STAGE = [&](int p) {
    const int kc = p * 32;
    __bf16* base = smem + (p % 3) * 10240;
    async16(Aq + (size_t)rA * 512 + kc + kA, base + (wv * 64) * 8);
    async16(Ak + (size_t)rA * 512 + kc + kA, base + 2048 + (wv * 64) * 8);
    async16(Av + (size_t)rA * 512 + kc + kA, base + 4096 + (wv * 64) * 8);
    async16(Bx + (size_t)rB0 * 512 + kc + kB0, base + 6144 + (wv * 64) * 8);
    async16(Bx + (size_t)rB1 * 512 + kc + kB1, base + 6144 + (256 + wv * 64) * 8);
  };

  STAGE(0); STAGE(1);

#pragma unroll
  for (int p = 0; p < 16; p++) {
    if (p <= 13) {
      STAGE(p + 2);
      asm volatile("s_waitcnt vmcnt(10)" ::: "memory");
    } else if (p == 14) {
      asm volatile("s_waitcnt vmcnt(5)" ::: "memory");
    } else {
      asm volatile("s_waitcnt vmcnt(0)" ::: "memory");
    }
    __builtin_amdgcn_s_barrier();
    __builtin_amdgcn_sched_barrier(0);
    const __bf16* base = smem + (p % 3) * 10240;
    bf16x8_t bfr[4];
#pragma unroll
    for (int j = 0; j < 4; j++)
      bfr[j] = *(const bf16x8_t*)(base + 6144 + (wn + j * 16 + l16) * 32 + swq);
#pragma unroll
    for (int m = 0; m < 3; m++) {
      bf16x8_t af[2];
#pragma unroll
      for (int i = 0; i < 2; i++)
        af[i] = *(const bf16x8_t*)(base + m * 2048 + (wm + i * 16 + l16) * 32 + swq);
      __builtin_amdgcn_s_setprio(1);
#pragma unroll
      for (int i = 0; i < 2; i++)
#pragma unroll
        for (int j = 0; j < 4; j++)
          acc[m][i][j] = __builtin_amdgcn_mfma_f32_16x16x32_bf16(af[i], bfr[j], acc[m][i][j], 0, 0, 0);
      __builtin_amdgcn_s_setprio(0);
    }
    __builtin_amdgcn_sched_barrier(0);
    __builtin_amdgcn_s_barrier();   // buffer p%3 free for reuse
  }

  // ---- epilogues (sequential, reuse smem; all coalesced via LDS transpose) ----
  const float qscale = 0.125f * 1.44269504f;   // HD^-0.5 * log2(e), folded into Q
#pragma unroll
  for (int mat = 0; mat < 2; mat++) {
    const float* bias = (mat == 0) ? qb : kb;
    const float sc = (mat == 0) ? qscale : 1.0f;
    __bf16* dst = (mat == 0) ? qT : kT;
#pragma unroll
    for (int i = 0; i < 2; i++) {
      const int crow = wm + i * 16 + quad * 4;
      const int o = m0 + crow;
      float b0 = bias[o], b1 = bias[o + 1], b2 = bias[o + 2], b3 = bias[o + 3];
#pragma unroll
      for (int j = 0; j < 4; j++) {
        const int nl = wn + j * 16 + l16;
        bf16x4_t pk;
        pk[0] = f2b((acc[mat][i][j][0] + b0) * sc);
        pk[1] = f2b((acc[mat][i][j][1] + b1) * sc);
        pk[2] = f2b((acc[mat][i][j][2] + b2) * sc);
        pk[3] = f2b((acc[mat][i][j][3] + b3) * sc);
        *(bf16x4_t*)(smem + nl * 72 + crow) = pk;
      }
    }
    __syncthreads();
#pragma unroll
    for (int it = 0; it < 4; it++) {
      const int n = it * 32 + (tid >> 3);
      const int c = (tid & 7) * 8;
      *(bf16x8_t*)(dst + ((size_t)b * N_PIX + n0 + n) * 512 + m0 + c) =
          *(const bf16x8_t*)(smem + n * 72 + c);
    }
    __syncthreads();
  }
  // V: [c][n] layout via stride-132 transpose
#pragma unroll
  for (int i = 0; i < 2; i++) {
    const int crow = wm + i * 16 + quad * 4;
    const int o = m0 + crow;
    float b0 = vb[o], b1 = vb[o + 1], b2 = vb[o + 2], b3 = vb[o + 3];
#pragma unroll
    for (int j = 0; j < 4; j++) {
      const int nl = wn + j * 16 + l16;
      smem[(crow + 0) * 132 + nl] = f2b(acc[2][i][j][0] + b0);
      smem[(crow + 1) * 132 + nl] = f2b(acc[2][i][j][1] + b1);
      smem[(crow + 2) * 132 + nl] = f2b(acc[2][i][j][2] + b2);
      smem[(crow + 3) * 132 + nl] = f2b(acc[2][i][j][3] + b3);
    }
  }
  __syncthreads();
  {
    const int c = tid >> 2;
    const int nch = (tid & 3) * 32;
    __bf16* vd = vbuf + ((size_t)b * 512 + m0 + c) * N_PIX + n0 + nch;
#pragma unroll
    for (int k = 0; k < 4; k++)
      *(bf16x8_t*)(vd + k * 8) = *(const bf16x8_t*)(smem + c * 132 + nch + k * 8);
  }
}

// ---------------- attention: 32 q/wave, permuted V, double-buffered, LDS-transposed out ----------------
// Raw barriers with lgkm-only drain: the 2-ahead K/V global prefetch stays in flight.
__global__ __launch_bounds__(256, 2) void attn_kernel(
    const __bf16* __restrict__ qT, const __bf16* __restrict__ kT,
    const __bf16* __restrict__ vbuf, __bf16* __restrict__ aT)
{
  __shared__ __align__(16) __bf16 Ks[2][64 * 72];
  __shared__ __align__(16) __bf16 Vp[2][64 * 72];
  const int bh = blockIdx.x;
  const int b = bh >> 3, head = bh & 7;
  const int n0 = blockIdx.y * 128;
  const int tid = threadIdx.x, lane = tid & 63, wv = tid >> 6;
  const int quad = lane >> 4, l16 = lane & 15;

  bf16x8_t qf[2][2];
#pragma unroll
  for (int qt = 0; qt < 2; qt++) {
    const __bf16* qp = qT + ((size_t)b * N_PIX + n0 + wv * 32 + qt * 16 + l16) * 512 + head * 64;
    qf[qt][0] = *(const bf16x8_t*)(qp + quad * 8);
    qf[qt][1] = *(const bf16x8_t*)(qp + 32 + quad * 8);
  }

  const __bf16* kp = kT + ((size_t)b * N_PIX) * 512 + head * 64;
  const __bf16* vp = vbuf + ((size_t)b * 512 + head * 64) * N_PIX;

  const int srow = tid >> 2, scol = (tid & 3) * 16;
  const int pr0 = scol >> 5, hh0 = (scol >> 4) & 1;
  const int pos0 = pr0 * 32 + ((scol >> 2) & 3) * 8 + hh0 * 4;
  const int mc1 = scol + 8;
  const int pr1 = mc1 >> 5, hh1 = (mc1 >> 4) & 1;
  const int pos1 = pr1 * 32 + ((mc1 >> 2) & 3) * 8 + hh1 * 4;

  bf16x8_t kreg0 = *(const bf16x8_t*)(kp + (size_t)srow * 512 + scol);
  bf16x8_t kreg1 = *(const bf16x8_t*)(kp + (size_t)srow * 512 + scol + 8);
  bf16x8_t vreg0 = *(const bf16x8_t*)(vp + (size_t)srow * N_PIX + scol);
  bf16x8_t vreg1 = *(const bf16x8_t*)(vp + (size_t)srow * N_PIX + scol + 8);
  {
    *(bf16x8_t*)(Ks[0] + srow * 72 + scol)     = kreg0;
    *(bf16x8_t*)(Ks[0] + srow * 72 + scol + 8) = kreg1;
    bf16x4_t lo, hi;
#pragma unroll
    for (int r = 0; r < 4; r++) { lo[r] = vreg0[r]; hi[r] = vreg0[4 + r]; }
    *(bf16x4_t*)(Vp[0] + srow * 72 + pos0)     = lo;
    *(bf16x4_t*)(Vp[0] + srow * 72 + pos0 + 8) = hi;
#pragma unroll
    for (int r = 0; r < 4; r++) { lo[r] = vreg1[r]; hi[r] = vreg1[4 + r]; }
    *(bf16x4_t*)(Vp[0] + srow * 72 + pos1)     = lo;
    *(bf16x4_t*)(Vp[0] + srow * 72 + pos1 + 8) = hi;
  }
  kreg0 = *(const bf16x8_t*)(kp + (size_t)(64 + srow) * 512 + scol);
  kreg1 = *(const bf16x8_t*)(kp + (size_t)(64 + srow) * 512 + scol + 8);
  vreg0 = *(const bf16x8_t*)(vp + (size_t)srow * N_PIX + 64 + scol);
  vreg1 = *(const bf16x8_t*)(vp + (size_t)srow * N_PIX + 64 + scol + 8);
  // LDS-write visibility only; tile-1 global prefetch stays in flight
  asm volatile("s_waitcnt lgkmcnt(0)" ::: "memory");
  __builtin_amdgcn_s_barrier();
  __builtin_amdgcn_sched_barrier(0);

  const f32x4_t zero = {0.f, 0.f, 0.f, 0.f};
  f32x4_t oacc[2][4];
#pragma unroll
  for (int qt = 0; qt < 2; qt++)
#pragma unroll
    for (int jc = 0; jc < 4; jc++) oacc[qt][jc] = zero;
  f32x4_t lsum4[2] = {zero, zero};

  for (int mt = 0; mt < 16; mt++) {
    const int cur = mt & 1, nxt = cur ^ 1;
    const __bf16* Kc = Ks[cur];
    const __bf16* Vc = Vp[cur];

    f32x4_t sacc[2][4];
    __builtin_amdgcn_s_setprio(1);
#pragma unroll
    for (int mb = 0; mb < 4; mb++) {
      bf16x8_t kf0 = *(const bf16x8_t*)(Kc + (mb * 16 + l16) * 72 + quad * 8);
      bf16x8_t kf1 = *(const bf16x8_t*)(Kc + (mb * 16 + l16) * 72 + 32 + quad * 8);
#pragma unroll
      for (int qt = 0; qt < 2; qt++) {
        f32x4_t s = zero;
        s = __builtin_amdgcn_mfma_f32_16x16x32_bf16(kf0, qf[qt][0], s, 0, 0, 0);
        s = __builtin_amdgcn_mfma_f32_16x16x32_bf16(kf1, qf[qt][1], s, 0, 0, 0);
        sacc[qt][mb] = s;
      }
    }
    __builtin_amdgcn_s_setprio(0);

    bf16x8_t pf[2][2];
#pragma unroll
    for (int qt = 0; qt < 2; qt++) {
      float p[4][4];
#pragma unroll
      for (int mb = 0; mb < 4; mb++)
#pragma unroll
        for (int r = 0; r < 4; r++) {
          p[mb][r] = __builtin_amdgcn_exp2f(sacc[qt][mb][r]);
          lsum4[qt][r] += p[mb][r];
        }
#pragma unroll
      for (int pr = 0; pr < 2; pr++) {
        u32x4_t u;
        u[0] = pack_trunc(p[2 * pr][0],     p[2 * pr][1]);
        u[1] = pack_trunc(p[2 * pr][2],     p[2 * pr][3]);
        u[2] = pack_trunc(p[2 * pr + 1][0], p[2 * pr + 1][1]);
        u[3] = pack_trunc(p[2 * pr + 1][2], p[2 * pr + 1][3]);
        pf[qt][pr] = __builtin_bit_cast(bf16x8_t, u);
      }
    }

    __builtin_amdgcn_s_setprio(1);
#pragma unroll
    for (int jc = 0; jc < 4; jc++) {
      const int vrow = (jc * 16 + l16) * 72;
#pragma unroll
      for (int pr = 0; pr < 2; pr++) {
        bf16x8_t vf = *(const bf16x8_t*)(Vc + vrow + pr * 32 + quad * 8);
#pragma unroll
        for (int qt = 0; qt < 2; qt++)
          oacc[qt][jc] = __builtin_amdgcn_mfma_f32_16x16x32_bf16(vf, pf[qt][pr], oacc[qt][jc], 0, 0, 0);
      }
    }
    __builtin_amdgcn_s_setprio(0);

    if (mt < 15) {
      *(bf16x8_t*)(Ks[nxt] + srow * 72 + scol)     = kreg0;
      *(bf16x8_t*)(Ks[nxt] + srow * 72 + scol + 8) = kreg1;
      bf16x4_t lo, hi;
#pragma unroll
      for (int r = 0; r < 4; r++) { lo[r] = vreg0[r]; hi[r] = vreg0[4 + r]; }
      *(bf16x4_t*)(Vp[nxt] + srow * 72 + pos0)     = lo;
      *(bf16x4_t*)(Vp[nxt] + srow * 72 + pos0 + 8) = hi;
#pragma unroll
      for (int r = 0; r < 4; r++) { lo[r] = vreg1[r]; hi[r] = vreg1[4 + r]; }
      *(bf16x4_t*)(Vp[nxt] + srow * 72 + pos1)     = lo;
      *(bf16x4_t*)(Vp[nxt] + srow * 72 + pos1 + 8) = hi;
      if (mt < 14) {
        kreg0 = *(const bf16x8_t*)(kp + (size_t)((mt + 2) * 64 + srow) * 512 + scol);
        kreg1 = *(const bf16x8_t*)(kp + (size_t)((mt + 2) * 64 + srow) * 512 + scol + 8);
        vreg0 = *(const bf16x8_t*)(vp + (size_t)srow * N_PIX + (mt + 2) * 64 + scol);
        vreg1 = *(const bf16x8_t*)(vp + (size_t)srow * N_PIX + (mt + 2) * 64 + scol + 8);
      }
      // LDS-write visibility only; next-tile global prefetch stays in flight
      asm volatile("s_waitcnt lgkmcnt(0)" ::: "memory");
      __builtin_amdgcn_s_barrier();
      __builtin_amdgcn_sched_barrier(0);
    }
  }

  // O epilogue: normalize, transpose through LDS (reuse Ks), coalesced stores
  __syncthreads();
  __bf16* Tr = &Ks[0][0];
#pragma unroll
  for (int qt = 0; qt < 2; qt++) {
    float lsum = lsum4[qt][0] + lsum4[qt][1] + lsum4[qt][2] + lsum4[qt][3];
    lsum += __shfl_xor(lsum, 16, 64);
    lsum += __shfl_xor(lsum, 32, 64);
    const float inv = 1.f / lsum;
    const int nl = wv * 32 + qt * 16 + l16;
#pragma unroll
    for (int jc = 0; jc < 4; jc++) {
      bf16x4_t o4;
#pragma unroll
      for (int r = 0; r < 4; r++) o4[r] = f2b(oacc[qt][jc][r] * inv);
      *(bf16x4_t*)(Tr + nl * 72 + jc * 16 + quad * 4) = o4;
    }
  }
  __syncthreads();
#pragma unroll
  for (int it = 0; it < 4; it++) {
    const int n = it * 32 + (tid >> 3);
    const int c = (tid & 7) * 8;
    *(bf16x8_t*)(aT + ((size_t)b * N_PIX + n0 + n) * 512 + head * 64 + c) =
        *(const bf16x8_t*)(Tr + n * 72 + c);
  }
}

// ---------------- proj gemm + bias + residual: 64x128 tiles, grid (8=b, 8=n, 8=m) ----------------
__global__ __launch_bounds__(256, 4) void gemm_proj_kernel(
    const __bf16* __restrict__ wp, const float* __restrict__ pb,
    const __bf16* __restrict__ aT, const float* __restrict__ x,
    float* __restrict__ out)
{
  __shared__ __align__(16) __bf16 smem[18432];   // 3 buffers x 6144 bf16 = 36 KB
  const int b = blockIdx.x;
  const int n0 = blockIdx.y * 128;
  const int m0 = blockIdx.z * 64;
  const __bf16* A = wp + (size_t)m0 * 512;
  const __bf16* B = aT + ((size_t)b * N_PIX + n0) * 512;
  f32x4_t acc[2][4];
  gemm_core_64(A, B, smem, acc);
  const int tid = threadIdx.x, lane = tid & 63, wv = tid >> 6;
  const int quad = lane >> 4, l16 = lane & 15;
  const int wm = (wv >> 1) * 32, wn = (wv & 1) * 64;
#pragma unroll
  for (int i = 0; i < 2; i++) {
    const int o = m0 + wm + i * 16 + quad * 4;
#pragma unroll
    for (int j = 0; j < 4; j++) {
      const int n = n0 + wn + j * 16 + l16;
#pragma unroll
      for (int r = 0; r < 4; r++) {
        size_t idx = ((size_t)b * 512 + o + r) * N_PIX + n;
        out[idx] = acc[i][j][r] + pb[o + r] + x[idx];
      }
    }
  }
}

extern "C" void kernel_launch(void* const* d_in, const int* in_sizes, int n_in,
                              void* d_out, int out_size, void* d_ws, size_t ws_size,
                              hipStream_t stream)
{
  (void)in_sizes; (void)n_in; (void)out_size; (void)ws_size;
  const float* x   = (const float*)d_in[0];
  const float* gnw = (const float*)d_in[1];
  const float* gnb = (const float*)d_in[2];
  const float* qw  = (const float*)d_in[3];
  const float* qb  = (const float*)d_in[4];
  const float* kw  = (const float*)d_in[5];
  const float* kb  = (const float*)d_in[6];
  const float* vw  = (const float*)d_in[7];
  const float* vb  = (const float*)d_in[8];
  const float* pw  = (const float*)d_in[9];
  const float* pb  = (const float*)d_in[10];
  float* out = (float*)d_out;

  char* ws = (char*)d_ws;
  __bf16* wb   = (__bf16*)(ws);                         // 2 MB
  __bf16* xnT  = (__bf16*)(ws + (size_t)(2  << 20));    // 8 MB
  __bf16* qTb  = (__bf16*)(ws + (size_t)(10 << 20));    // 8 MB
  __bf16* kTb  = (__bf16*)(ws + (size_t)(18 << 20));    // 8 MB
  __bf16* vbf  = (__bf16*)(ws + (size_t)(26 << 20));    // 8 MB
  __bf16* aT   = (__bf16*)(ws + (size_t)(34 << 20));    // 8 MB
  float2* psum = (float2*)(ws + (size_t)(42 << 20));    // 4 KB

  hipLaunchKernelGGL(prep_kernel, dim3(1536), dim3(256), 0, stream,
                     qw, kw, vw, pw, wb, x, psum);
  hipLaunchKernelGGL(gn_apply_kernel, dim3(32, 8, 2), dim3(256), 0, stream, x, psum, gnw, gnb, xnT);
  hipLaunchKernelGGL(gemm_qkv_kernel, dim3(8, 8, 8), dim3(256), 0, stream,
                     wb, qb, kb, vb, xnT, qTb, kTb, vbf);
  hipLaunchKernelGGL(attn_kernel, dim3(64, 8), dim3(256), 0, stream, qTb, kTb, vbf, aT);
  hipLaunchKernelGGL(gemm_proj_kernel, dim3(8, 8, 8), dim3(256), 0, stream,
                     wb + (size_t)3 * 512 * 512, pb, aT, x, out);
}